// Round 3
// baseline (84.809 us; speedup 1.0000x reference)
//
#include <hip/hip_runtime.h>
#include <math.h>

// Problem constants (static shapes from setup_inputs; all arrays are float32)
#define B_   2
#define T_   8
#define R_   128
#define NP_  32768
#define F_   5
#define S_   32           // num_sample
#define NBT  (B_ * T_)    // 16
#define NROW (NBT * R_)   // 2048
#define WV_  8            // waves per block = segments per roi-group
#define RPB  4            // rois per block (all tested by every wave)
#define NBLK (NROW / RPB) // 512 blocks -> 16 waves/CU (4/SIMD)
#define SEGPTS (NP_ / WV_)   // 4096 points per wave-segment
#define NIT  (SEGPTS / 512)  // 8 iterations (512 pts per iteration)

__device__ __forceinline__ int mbcnt64(unsigned long long m) {
    return __builtin_amdgcn_mbcnt_hi((unsigned)(m >> 32),
           __builtin_amdgcn_mbcnt_lo((unsigned)m, 0u));
}

// ---------- kernel 1: vectorized AoS->SoA xy transpose + per-row constant prep ----------
// T = max{ x : sqrtf(x) <= radius } makes the scan predicate sqrt-free yet
// bit-identical (sqrtf monotone + correctly rounded).
__global__ __launch_bounds__(256) void xy_transpose_prep(
    const float* __restrict__ points,  // [bt, Np, 5]
    const float* __restrict__ rois,    // [bt, R, 9]
    float2* __restrict__ xy,           // [bt, Np]
    float4* __restrict__ rowc)         // [row] = {cx, cy, T, 0}
{
    const int j = blockIdx.x * blockDim.x + threadIdx.x;
    if (j < NBT * NP_ / 4) {
        const float4* src = (const float4*)points + (size_t)j * 5;
        const float4 a = src[0], b = src[1], c = src[2], d = src[3], e = src[4];
        float4* dst = (float4*)xy + (size_t)j * 2;
        dst[0] = make_float4(a.x, a.y, b.y, b.z);   // pts 4j, 4j+1
        dst[1] = make_float4(c.z, c.w, d.w, e.x);   // pts 4j+2, 4j+3
    }
    if (j < NROW) {
        const int row = j;                 // row = bt*R + r
        const int bt  = row / R_;
        const int t   = bt % T_;
        const float* roi = rois + (size_t)row * 9;
        const float cx = roi[0], cy = roi[1];
        const float hx = roi[3] * 0.5f, hy = roi[4] * 0.5f;
        const float vx = roi[7], vy = roi[8];
        const float speed  = sqrtf(vx * vx + vy * vy);
        const float base_g = 1.05f * (1.0f + speed);
        const float expo   = (float)t / 5.0f;
        const float gamma  = fminf((float)pow((double)base_g, (double)expo), 2.5f);
        const float radius = sqrtf(hx * hx + hy * hy) * gamma;   // same as passing rounds
        // ulp-walk: largest float T with sqrtf(T) <= radius
        unsigned ut = __float_as_uint(radius * radius);
        while (sqrtf(__uint_as_float(ut)) > radius) --ut;
        while (sqrtf(__uint_as_float(ut + 1u)) <= radius) ++ut;
        rowc[row] = make_float4(cx, cy, __uint_as_float(ut), 0.0f);
    }
}

// ---------- kernel 2 (fused, segment-parallel, 4 rois/wave): scan + merge + emit ----------
// One block (512 thr = 8 waves) owns 4 consecutive rois. Wave w scans segment w
// (4096 points, index order) for all 4 rois with the verified ballot/mbcnt
// ordered-insertion logic. Per-segment lists (<=32 each) merge via an 8-count
// prefix in LDS; concatenation order == global index order, and a segment with
// >32 local hits clamps safely. 512 blocks x 8 waves = 16 waves/CU; L2 read
// traffic halved vs 2-roi version (134 MB); no register copies in the pipeline
// (two-set unroll, no mid-loop break -> compiler schedules loads ahead).

// PROC1: test one float4 (= 2 consecutive points, indices base+2*lane[+1])
// against one roi. Strict numpy rounding: mul, mul, add separately (no fma).
#define PROC1(qq, base, rc, sel, hb)                                              \
    {                                                                             \
        const float ax = __fsub_rn(qq.x, rc.x), ay = __fsub_rn(qq.y, rc.y);       \
        const float bx = __fsub_rn(qq.z, rc.x), by = __fsub_rn(qq.w, rc.y);       \
        const float d2a = __fadd_rn(__fmul_rn(ax, ax), __fmul_rn(ay, ay));        \
        const float d2b = __fadd_rn(__fmul_rn(bx, bx), __fmul_rn(by, by));        \
        const bool p0 = (d2a <= rc.z), p1 = (d2b <= rc.z);                        \
        const unsigned long long m0 = __ballot(p0), m1 = __ballot(p1);            \
        if (m0 | m1) {                                                            \
            const int bb = sel + mbcnt64(m0) + mbcnt64(m1);                       \
            if (p0 && bb < S_) hb[bb] = (unsigned short)((base) + l2);            \
            if (p1) { const int s2 = bb + (p0 ? 1 : 0);                           \
                      if (s2 < S_) hb[s2] = (unsigned short)((base) + l2 + 1); }  \
            sel += __popcll(m0) + __popcll(m1);                                   \
        }                                                                         \
    }

// PROCQ: one float4 chunk (128 points starting at ib + kk*128) vs all 4 rois.
#define PROCQ(qq, kk, ib)                                                         \
    PROC1(qq, (ib) + (kk) * 128, rc0, sel0, hb0)                                  \
    PROC1(qq, (ib) + (kk) * 128, rc1, sel1, hb1)                                  \
    PROC1(qq, (ib) + (kk) * 128, rc2, sel2, hb2)                                  \
    PROC1(qq, (ib) + (kk) * 128, rc3, sel3, hb3)

#define LOAD4(r0, r1, r2, r3)                                                     \
    r0 = src[0]; r1 = src[64]; r2 = src[128]; r3 = src[192]; src += 256;

#define ITER(r0, r1, r2, r3, ib)                                                  \
    PROCQ(r0, 0, ib) PROCQ(r1, 1, ib) PROCQ(r2, 2, ib) PROCQ(r3, 3, ib)

__global__ __launch_bounds__(512, 4) void fused_scan_emit(
    const float2* __restrict__ xy,     // [bt, Np]
    const float4* __restrict__ rowc,   // [row] = {cx, cy, T, 0}
    const float* __restrict__ points,  // [bt, Np, 5]
    float* __restrict__ out)           // [B, R, T*S, 5]
{
    __shared__ unsigned short hitbuf[WV_][RPB][S_];   // 2 KB
    __shared__ int cnt[WV_][RPB];
    const int w    = threadIdx.x >> 6;
    const int lane = threadIdx.x & 63;
    const int l2   = lane * 2;
    const int row0 = blockIdx.x * RPB;             // 4 consecutive rois, same bt
    const int bt   = row0 / R_;
    // lane-uniform loads -> compiler scalarizes (s_load), no VGPR cost
    const float4 rc0 = rowc[row0], rc1 = rowc[row0 + 1];
    const float4 rc2 = rowc[row0 + 2], rc3 = rowc[row0 + 3];
    unsigned short* hb0 = hitbuf[w][0];
    unsigned short* hb1 = hitbuf[w][1];
    unsigned short* hb2 = hitbuf[w][2];
    unsigned short* hb3 = hitbuf[w][3];
    const int segbase = w * SEGPTS;                // this wave's point range

    // coalesced stream: lane reads float4 = 2 points; 4 chunks (512 pts) per iter
    const float4* src = (const float4*)(xy + (size_t)bt * NP_) + (segbase >> 1) + lane;
    int sel0 = 0, sel1 = 0, sel2 = 0, sel3 = 0;

    // two-register-set pipeline, no copies, no break: iters 0..7
    float4 a0, a1, a2, a3, b0, b1, b2, b3;
    LOAD4(a0, a1, a2, a3)                          // iter 0
    int ib = segbase;
    #pragma unroll 1
    for (int it = 0; it < NIT - 2; it += 2) {
        LOAD4(b0, b1, b2, b3)                      // iter it+1
        ITER(a0, a1, a2, a3, ib)                   // iter it
        LOAD4(a0, a1, a2, a3)                      // iter it+2
        ITER(b0, b1, b2, b3, ib + 512)             // iter it+1
        ib += 1024;
    }
    LOAD4(b0, b1, b2, b3)                          // iter 7
    ITER(a0, a1, a2, a3, ib)                       // iter 6
    ITER(b0, b1, b2, b3, ib + 512)                 // iter 7

    if (lane == 0) {
        cnt[w][0] = (sel0 < S_) ? sel0 : S_;
        cnt[w][1] = (sel1 < S_) ? sel1 : S_;
        cnt[w][2] = (sel2 < S_) ? sel2 : S_;
        cnt[w][3] = (sel3 < S_) ? sel3 : S_;
    }
    __syncthreads();   // all segment lists + counts visible

    // emission: 128 output slots per block (4 rois x 32)
    if (threadIdx.x < RPB * S_) {
        const int ri = threadIdx.x >> 5;           // roi within block
        const int s  = threadIdx.x & 31;
        int seg = -1, local = 0, acc = 0;
        #pragma unroll
        for (int g = 0; g < WV_; ++g) {
            const int na = acc + cnt[g][ri];
            if (seg < 0 && s < na) { seg = g; local = s - acc; }
            acc = na;
        }
        const int row = row0 + ri;
        const int r = row % R_;
        const int t = bt % T_;
        const int b = bt / T_;
        float* o = out + ((((size_t)b * R_ + r) * T_ + t) * S_ + s) * (size_t)F_;
        if (seg >= 0) {
            const int pi = hitbuf[seg][ri][local];
            const float* p = points + ((size_t)bt * NP_ + pi) * F_;
            o[0] = p[0]; o[1] = p[1]; o[2] = p[2]; o[3] = p[3]; o[4] = p[4];
        } else {
            o[0] = 0.0f; o[1] = 0.0f; o[2] = 0.0f; o[3] = 0.0f; o[4] = 0.0f;
        }
    }
}

extern "C" void kernel_launch(void* const* d_in, const int* in_sizes, int n_in,
                              void* d_out, int out_size, void* d_ws, size_t ws_size,
                              hipStream_t stream) {
    const float* points = (const float*)d_in[0];
    const float* rois   = (const float*)d_in[1];
    float* out = (float*)d_out;

    // workspace layout (~4.2 MB): xy transpose + per-row constants
    char* ws = (char*)d_ws;
    float2* xy   = (float2*)ws;                 // 4,194,304 B
    float4* rowc = (float4*)(ws + 4194304);     //    32,768 B

    // 1) vectorized transpose + per-row constants (fused)
    xy_transpose_prep<<<(NBT * NP_ / 4 + 255) / 256, 256, 0, stream>>>(points, rois, xy, rowc);

    // 2) fused segment-parallel scan (4 rois/wave) + in-LDS merge + emission
    fused_scan_emit<<<NBLK, 512, 0, stream>>>(xy, rowc, points, out);
}

// Round 4
// 83.195 us; speedup vs baseline: 1.0194x; 1.0194x over previous
//
#include <hip/hip_runtime.h>
#include <math.h>

// Problem constants (static shapes from setup_inputs; all arrays are float32)
#define B_   2
#define T_   8
#define R_   128
#define NP_  32768
#define F_   5
#define S_   32           // num_sample
#define NBT  (B_ * T_)    // 16
#define NROW (NBT * R_)   // 2048
#define WV_  8            // waves per block = segments per roi-pair
#define SEGPTS (NP_ / WV_)   // 4096 points per wave-segment
#define NIT  (SEGPTS / 512)  // 8 iterations (512 pts per iteration)

typedef float f2 __attribute__((ext_vector_type(2)));

__device__ __forceinline__ int mbcnt64(unsigned long long m) {
    return __builtin_amdgcn_mbcnt_hi((unsigned)(m >> 32),
           __builtin_amdgcn_mbcnt_lo((unsigned)m, 0u));
}

// ---------- kernel 1: vectorized AoS->SoA xy transpose + per-row constant prep ----------
// Pair-SoA layout: each output float4 = {x_{2j}, x_{2j+1}, y_{2j}, y_{2j+1}}
// so the scan can use packed-fp32 (v_pk_*) on aligned 64-bit x/y pairs.
// Same loads/stores as the verified version, components permuted only.
// T = max{ x : sqrtf(x) <= radius } makes the scan predicate sqrt-free yet
// bit-identical (sqrtf monotone + correctly rounded).
__global__ __launch_bounds__(256) void xy_transpose_prep(
    const float* __restrict__ points,  // [bt, Np, 5]
    const float* __restrict__ rois,    // [bt, R, 9]
    float4* __restrict__ xy,           // [bt, Np/2] pair-SoA
    float4* __restrict__ rowc)         // [row] = {cx, cy, T, 0}
{
    const int j = blockIdx.x * blockDim.x + threadIdx.x;
    if (j < NBT * NP_ / 4) {
        const float4* src = (const float4*)points + (size_t)j * 5;
        const float4 a = src[0], b = src[1], c = src[2], d = src[3], e = src[4];
        float4* dst = xy + (size_t)j * 2;
        dst[0] = make_float4(a.x, b.y, a.y, b.z);   // {x0,x1,y0,y1} of pts 4j,4j+1
        dst[1] = make_float4(c.z, d.w, c.w, e.x);   // {x2,x3,y2,y3} of pts 4j+2,4j+3
    }
    if (j < NROW) {
        const int row = j;                 // row = bt*R + r
        const int bt  = row / R_;
        const int t   = bt % T_;
        const float* roi = rois + (size_t)row * 9;
        const float cx = roi[0], cy = roi[1];
        const float hx = roi[3] * 0.5f, hy = roi[4] * 0.5f;
        const float vx = roi[7], vy = roi[8];
        const float speed  = sqrtf(vx * vx + vy * vy);
        const float base_g = 1.05f * (1.0f + speed);
        const float expo   = (float)t / 5.0f;
        const float gamma  = fminf((float)pow((double)base_g, (double)expo), 2.5f);
        const float radius = sqrtf(hx * hx + hy * hy) * gamma;   // same as passing rounds
        // ulp-walk: largest float T with sqrtf(T) <= radius
        unsigned ut = __float_as_uint(radius * radius);
        while (sqrtf(__uint_as_float(ut)) > radius) --ut;
        while (sqrtf(__uint_as_float(ut + 1u)) <= radius) ++ut;
        rowc[row] = make_float4(cx, cy, __uint_as_float(ut), 0.0f);
    }
}

// ---------- kernel 2 (fused, segment-parallel): packed-fp32 scan + merge + emit ----------
// Round-2 geometry (best measured): one block (512 thr = 8 waves) per roi-PAIR,
// wave w scans segment w (4096 pts, index order) for both rois with the
// verified ballot/mbcnt ordered-insertion logic. Round-3 pipeline (two register
// sets, no copies, no break). Predicate math in ext-vector float2 under
// fp contract(off): fsub/fmul/fadd per component, IEEE-RNE — bit-identical to
// the __f*_rn version — letting the backend emit v_pk_add/mul_f32 (2 f32/instr).

// PROC1: test one float4 (pair-SoA: x-pair, y-pair = pts base+2*lane, +1)
// against one roi.
#define PROC1(qq, base, rc, sel, hb)                                              \
    {                                                                             \
        const f2 px = {qq.x, qq.y}, py = {qq.z, qq.w};                            \
        const f2 dx = px - (f2){rc.x, rc.x};                                      \
        const f2 dy = py - (f2){rc.y, rc.y};                                      \
        const f2 d2 = dx * dx + dy * dy;      /* contract(off): mul,mul,add */    \
        const bool p0 = (d2.x <= rc.z), p1 = (d2.y <= rc.z);                      \
        const unsigned long long m0 = __ballot(p0), m1 = __ballot(p1);            \
        if (m0 | m1) {                                                            \
            const int bb = sel + mbcnt64(m0) + mbcnt64(m1);                       \
            if (p0 && bb < S_) hb[bb] = (unsigned short)((base) + l2);            \
            if (p1) { const int s2 = bb + (p0 ? 1 : 0);                           \
                      if (s2 < S_) hb[s2] = (unsigned short)((base) + l2 + 1); }  \
            sel += __popcll(m0) + __popcll(m1);                                   \
        }                                                                         \
    }

// PROCQ: one float4 chunk (128 points starting at ib + kk*128) vs both rois.
#define PROCQ(qq, kk, ib)                                                         \
    PROC1(qq, (ib) + (kk) * 128, rc0, sel0, hb0)                                  \
    PROC1(qq, (ib) + (kk) * 128, rc1, sel1, hb1)

#define LOAD4(r0, r1, r2, r3)                                                     \
    r0 = src[0]; r1 = src[64]; r2 = src[128]; r3 = src[192]; src += 256;

#define ITER(r0, r1, r2, r3, ib)                                                  \
    PROCQ(r0, 0, ib) PROCQ(r1, 1, ib) PROCQ(r2, 2, ib) PROCQ(r3, 3, ib)

__global__ __launch_bounds__(512, 8) void fused_scan_emit(
    const float4* __restrict__ xy,     // [bt, Np/2] pair-SoA
    const float4* __restrict__ rowc,   // [row] = {cx, cy, T, 0}
    const float* __restrict__ points,  // [bt, Np, 5]
    float* __restrict__ out)           // [B, R, T*S, 5]
{
#pragma clang fp contract(off)
    __shared__ unsigned short hitbuf[WV_][2][S_];   // 1 KB
    __shared__ int cnt[WV_][2];
    const int w    = threadIdx.x >> 6;
    const int lane = threadIdx.x & 63;
    const int l2   = lane * 2;
    const int row0 = blockIdx.x * 2;               // one roi-pair per block
    const int row1 = row0 + 1;
    const int bt   = row0 / R_;
    const float4 rc0 = rowc[row0], rc1 = rowc[row1];
    unsigned short* hb0 = hitbuf[w][0];
    unsigned short* hb1 = hitbuf[w][1];
    const int segbase = w * SEGPTS;                // this wave's point range

    // coalesced stream: lane reads float4 = 2 points; 4 chunks (512 pts) per iter
    const float4* src = xy + ((size_t)bt * NP_ + segbase) / 2 + lane;
    int sel0 = 0, sel1 = 0;

    // two-register-set pipeline, no copies, no break: iters 0..7
    float4 a0, a1, a2, a3, b0, b1, b2, b3;
    LOAD4(a0, a1, a2, a3)                          // iter 0
    int ib = segbase;
    #pragma unroll 1
    for (int it = 0; it < NIT - 2; it += 2) {
        LOAD4(b0, b1, b2, b3)                      // iter it+1
        ITER(a0, a1, a2, a3, ib)                   // iter it
        LOAD4(a0, a1, a2, a3)                      // iter it+2
        ITER(b0, b1, b2, b3, ib + 512)             // iter it+1
        ib += 1024;
    }
    LOAD4(b0, b1, b2, b3)                          // iter 7
    ITER(a0, a1, a2, a3, ib)                       // iter 6
    ITER(b0, b1, b2, b3, ib + 512)                 // iter 7

    if (lane == 0) {
        cnt[w][0] = (sel0 < S_) ? sel0 : S_;
        cnt[w][1] = (sel1 < S_) ? sel1 : S_;
    }
    __syncthreads();   // all segment lists + counts visible

    // emission: 64 output slots per block (2 rois x 32); first wave handles them
    if (threadIdx.x < 64) {
        const int half = lane >> 5;                // 0 -> roi0, 1 -> roi1
        const int s    = lane & 31;
        int seg = -1, local = 0, acc = 0;
        #pragma unroll
        for (int g = 0; g < WV_; ++g) {
            const int na = acc + cnt[g][half];
            if (seg < 0 && s < na) { seg = g; local = s - acc; }
            acc = na;
        }
        const int row = half ? row1 : row0;
        const int r = row % R_;
        const int t = bt % T_;
        const int b = bt / T_;
        float* o = out + ((((size_t)b * R_ + r) * T_ + t) * S_ + s) * (size_t)F_;
        if (seg >= 0) {
            const int pi = hitbuf[seg][half][local];
            const float* p = points + ((size_t)bt * NP_ + pi) * F_;
            o[0] = p[0]; o[1] = p[1]; o[2] = p[2]; o[3] = p[3]; o[4] = p[4];
        } else {
            o[0] = 0.0f; o[1] = 0.0f; o[2] = 0.0f; o[3] = 0.0f; o[4] = 0.0f;
        }
    }
}

extern "C" void kernel_launch(void* const* d_in, const int* in_sizes, int n_in,
                              void* d_out, int out_size, void* d_ws, size_t ws_size,
                              hipStream_t stream) {
    const float* points = (const float*)d_in[0];
    const float* rois   = (const float*)d_in[1];
    float* out = (float*)d_out;

    // workspace layout (~4.2 MB): pair-SoA xy + per-row constants
    char* ws = (char*)d_ws;
    float4* xy   = (float4*)ws;                 // 4,194,304 B
    float4* rowc = (float4*)(ws + 4194304);     //    32,768 B

    // 1) vectorized transpose (pair-SoA) + per-row constants (fused)
    xy_transpose_prep<<<(NBT * NP_ / 4 + 255) / 256, 256, 0, stream>>>(points, rois, xy, rowc);

    // 2) fused segment-parallel packed-fp32 scan + in-LDS merge + emission
    fused_scan_emit<<<NROW / 2, 512, 0, stream>>>(xy, rowc, points, out);
}